// Round 7
// baseline (183.154 us; speedup 1.0000x reference)
//
#include <hip/hip_runtime.h>

typedef unsigned short u16;
typedef unsigned int u32;
typedef __attribute__((ext_vector_type(8))) short bf16x8;
typedef __attribute__((ext_vector_type(4))) float f32x4;

__device__ __forceinline__ u16 f2bf(float f) {
    u32 u = __builtin_bit_cast(u32, f);
    u += 0x7FFFu + ((u >> 16) & 1u);
    return (u16)(u >> 16);
}
__device__ __forceinline__ float bf2f(u16 s) {
    u32 u = ((u32)s) << 16;
    return __builtin_bit_cast(float, u);
}
__device__ __forceinline__ float sigm(float x) {
    return 1.0f / (1.0f + __expf(-x));
}
__device__ __forceinline__ void gload16(const u16* g, u16* l) {
    __builtin_amdgcn_global_load_lds(
        (const __attribute__((address_space(1))) void*)g,
        (__attribute__((address_space(3))) void*)l, 16, 0, 0);
}

// ---------------- P1: x (B,C,H,W) fp32 -> x' [p][c] bf16, p=(b*64+h)*64+w ----
__global__ __launch_bounds__(256) void transpose_in(const float* __restrict__ x,
                                                    u16* __restrict__ xp) {
    __shared__ float tile[64][65];
    int bid = blockIdx.x;
    int ct = bid & 3, h = (bid >> 2) & 63, b = bid >> 8;
    int t = threadIdx.x;
    int tr = t >> 4, tc = t & 15;
    const float* src = x + (((size_t)(b * 256 + ct * 64) * 64 + h) * 64);
#pragma unroll
    for (int i = 0; i < 4; ++i) {
        int c = tr + i * 16;
        float4 v = *(const float4*)(src + (size_t)c * 4096 + tc * 4);
        tile[c][tc * 4 + 0] = v.x;
        tile[c][tc * 4 + 1] = v.y;
        tile[c][tc * 4 + 2] = v.z;
        tile[c][tc * 4 + 3] = v.w;
    }
    __syncthreads();
    u16* dst = xp + ((size_t)((b * 64 + h) * 64)) * 256 + ct * 64;
#pragma unroll
    for (int i = 0; i < 4; ++i) {
        int w = tr + i * 16;
        ushort4 o;
        o.x = f2bf(tile[tc * 4 + 0][w]);
        o.y = f2bf(tile[tc * 4 + 1][w]);
        o.z = f2bf(tile[tc * 4 + 2][w]);
        o.w = f2bf(tile[tc * 4 + 3][w]);
        *(ushort4*)(dst + (size_t)w * 256 + tc * 4) = o;
    }
}

// ---------------- weight prep ------------------------------------------------
__global__ __launch_bounds__(256) void prep_w(const float* __restrict__ qw,
                                              const float* __restrict__ qb,
                                              const float* __restrict__ fw,
                                              const float* __restrict__ fb,
                                              float* __restrict__ wq0,
                                              u16* __restrict__ wkv,
                                              float* __restrict__ bkv,
                                              u16* __restrict__ wf,
                                              float* __restrict__ bff) {
    int i = blockIdx.x * 256 + threadIdx.x;
    if (i < 513 * 256) {
        int o = i >> 8, c = i & 255;
        float v = qw[i];
        if (o == 0) wq0[c] = v;
        else        wkv[(size_t)(o - 1) * 256 + c] = f2bf(v);
    }
    if (i < 65536) wf[i] = f2bf(fw[i]);
    if (i < 512)   bkv[i] = qb[i + 1];
    if (i < 256)   bff[i] = fb[i];
}

// ---------------- fused attn v3b: q-dot + softmax + y=sc^T X + ctx=Wk*y + ----
// ----------------             val GEMM (pipelined W prefetch) + gate ---------
// Block = 128 rows = 2 lines. 512 threads (8 waves).
// Key GEMM eliminated algebraically: ctx = Wk*(sc^T X) + bk (exact reorder).
template <int AXIS>
__global__ __launch_bounds__(512, 3) void qkv_attn(
    const u16* __restrict__ A, const u16* __restrict__ Bw,
    const float* __restrict__ bkv, const float* __restrict__ wq0,
    u16* __restrict__ G) {
    __shared__ alignas(16) u16 Asm[128 * 256];
    __shared__ float ql[128];
    __shared__ float sc[128];
    __shared__ alignas(16) float ys[2][256];
    __shared__ alignas(16) float ctxs[2][256];
    int t = threadIdx.x, lane = t & 63, wv = t >> 6;
    int beta = blockIdx.x;
    auto prow = [&](int r) -> size_t {
        if (AXIS == 0) return (size_t)beta * 128 + r;
        else           return (size_t)(beta >> 5) * 4096 + (size_t)(r & 63) * 64 +
                              ((beta & 31) * 2) + (r >> 6);
    };
    // ---- stage A panel; swizzle: stored chunk = src chunk ^ (row&7) ----
    {
#pragma unroll
        for (int i = 0; i < 8; ++i) {
            int row = i * 16 + wv * 2 + (lane >> 5);
            int slot = (lane & 31) ^ (row & 7);
            gload16(A + prow(row) * 256 + slot * 8, &Asm[(i * 16 + wv * 2) * 256]);
        }
    }
    __syncthreads();
    // ---- q-dot: 4 threads per row ----
    {
        int row = t >> 2, g = t & 3;
        const float* wp = wq0 + g * 64;
        float a = 0.f;
#pragma unroll
        for (int cc = 0; cc < 8; ++cc) {
            int slot = (g * 8 + cc) ^ (row & 7);
            bf16x8 v = *(const bf16x8*)&Asm[row * 256 + slot * 8];
#pragma unroll
            for (int j = 0; j < 8; ++j) a += bf2f((u16)v[j]) * wp[cc * 8 + j];
        }
        a += __shfl_xor(a, 1);
        a += __shfl_xor(a, 2);
        if (g == 0) ql[row] = a;
    }
    __syncthreads();
    // ---- softmax per line (waves 0,1) ----
    if (t < 128) {
        float qv = ql[t];
        float m = qv;
#pragma unroll
        for (int off = 32; off > 0; off >>= 1) m = fmaxf(m, __shfl_xor(m, off));
        float e = __expf(qv - m);
        float s = e;
#pragma unroll
        for (int off = 32; off > 0; off >>= 1) s += __shfl_xor(s, off);
        sc[t] = e / s;
    }
    __syncthreads();
    // ---- y[line][k] = sum_p sc[p]*X[p][k] ----
    // line = t>>8, chunk = (t&255)>>3 (all 32 chunks), sub = t&7 (8 rows each)
    {
        int line = t >> 8;
        int chunk = (t & 255) >> 3;
        int sub = t & 7;
        float part[8] = {0.f, 0.f, 0.f, 0.f, 0.f, 0.f, 0.f, 0.f};
#pragma unroll
        for (int i = 0; i < 8; ++i) {
            int row = line * 64 + sub * 8 + i;   // row&7 == i
            int slot = chunk ^ i;
            bf16x8 xv = *(const bf16x8*)&Asm[row * 256 + slot * 8];
            float scp = sc[row];
#pragma unroll
            for (int j = 0; j < 8; ++j) part[j] += bf2f((u16)xv[j]) * scp;
        }
#pragma unroll
        for (int off = 1; off < 8; off <<= 1)
#pragma unroll
            for (int j = 0; j < 8; ++j) part[j] += __shfl_xor(part[j], off);
        if (sub == 0) {
            f32x4 lo = {part[0], part[1], part[2], part[3]};
            f32x4 hi = {part[4], part[5], part[6], part[7]};
            *(f32x4*)&ys[line][chunk * 8] = lo;
            *(f32x4*)&ys[line][chunk * 8 + 4] = hi;
        }
    }
    __syncthreads();
    // ---- ctx[line][c] = sum_k ys[line][k]*Wk[c][k] + bk[c] ----
    {
        int line = t >> 8, c = t & 255;
        const u16* wk = Bw + (size_t)c * 256;
        float a = 0.f;
#pragma unroll
        for (int kc = 0; kc < 32; ++kc) {
            bf16x8 w = *(const bf16x8*)(wk + kc * 8);
#pragma unroll
            for (int j = 0; j < 8; ++j) a += bf2f((u16)w[j]) * ys[line][kc * 8 + j];
        }
        ctxs[line][c] = a + bkv[c];
    }
    __syncthreads();
    // ---- val GEMM (2 ot of 128 ch) with ping-pong W prefetch + gate ----
    int rowhalf = wv >> 2, chq = wv & 3;
    int arow = lane & 15, kgrp = lane >> 4;
    const u16* Wv = Bw + ((size_t)(256 + chq * 32 + arow)) * 256 + kgrp * 8;
    bf16x8 wbuf[2][8];
    auto loadgrp = [&](bf16x8(&dst)[8], int ot, int g) {
#pragma unroll
        for (int kk = 0; kk < 4; ++kk)
#pragma unroll
            for (int mi = 0; mi < 2; ++mi)
                dst[kk * 2 + mi] = *(const bf16x8*)(Wv +
                    (size_t)(ot * 128 + mi * 16) * 256 + (g * 4 + kk) * 32);
    };
    f32x4 zero = {0.f, 0.f, 0.f, 0.f};
    f32x4 acc[2][4];
    loadgrp(wbuf[0], 0, 0);
#pragma unroll
    for (int Gi = 0; Gi < 4; ++Gi) {
        const int ot = Gi >> 1, g = Gi & 1;
        if (Gi < 3) loadgrp(wbuf[(Gi + 1) & 1], (Gi + 1) >> 1, (Gi + 1) & 1);
        __builtin_amdgcn_sched_barrier(0);
        if (g == 0) {
#pragma unroll
            for (int mi = 0; mi < 2; ++mi)
#pragma unroll
                for (int ni = 0; ni < 4; ++ni) acc[mi][ni] = zero;
        }
#pragma unroll
        for (int kk = 0; kk < 4; ++kk) {
            int ks = g * 4 + kk;
            bf16x8 bx[4];
#pragma unroll
            for (int ni = 0; ni < 4; ++ni) {
                int p = rowhalf * 64 + ni * 16 + arow;
                int slot = (ks * 4 + kgrp) ^ (p & 7);
                bx[ni] = *(const bf16x8*)&Asm[p * 256 + slot * 8];
            }
#pragma unroll
            for (int mi = 0; mi < 2; ++mi)
#pragma unroll
                for (int ni = 0; ni < 4; ++ni)
                    acc[mi][ni] = __builtin_amdgcn_mfma_f32_16x16x32_bf16(
                        wbuf[Gi & 1][kk * 2 + mi], bx[ni], acc[mi][ni], 0, 0, 0);
        }
        if (g == 1) {
            // gate: G[p][c..c+3] = x + sigmoid(v+bias)*ctx
#pragma unroll
            for (int mi = 0; mi < 2; ++mi) {
                int cv = ot * 128 + chq * 32 + mi * 16 + kgrp * 4;
                f32x4 bv = *(const f32x4*)&bkv[256 + cv];
                f32x4 cxv = *(const f32x4*)&ctxs[rowhalf][cv];
#pragma unroll
                for (int ni = 0; ni < 4; ++ni) {
                    int p = rowhalf * 64 + ni * 16 + arow;
                    int slot = (cv >> 3) ^ (p & 7);
                    ushort4 xv = *(const ushort4*)&Asm[p * 256 + slot * 8 + (cv & 7)];
                    ushort4 o;
                    o.x = f2bf(bf2f(xv.x) + sigm(acc[mi][ni][0] + bv[0]) * cxv[0]);
                    o.y = f2bf(bf2f(xv.y) + sigm(acc[mi][ni][1] + bv[1]) * cxv[1]);
                    o.z = f2bf(bf2f(xv.z) + sigm(acc[mi][ni][2] + bv[2]) * cxv[2]);
                    o.w = f2bf(bf2f(xv.w) + sigm(acc[mi][ni][3] + bv[3]) * cxv[3]);
                    *(ushort4*)(G + prow(p) * 256 + cv) = o;
                }
            }
        }
    }
}

// ---------------- fusion GEMM: MODE 1 = bf16 out, MODE 2 = fp32 transposed out
template <int MODE>
__global__ __launch_bounds__(256, 2) void gemm_k(
    const u16* __restrict__ A, const u16* __restrict__ Bw,
    const float* __restrict__ bias,
    u16* __restrict__ bOut, float* __restrict__ fOut) {
    int h = blockIdx.x;
    int xcd = h & 7, slot = h >> 3;
    int otile = slot & 1, ptile = xcd * 64 + (slot >> 1);
    __shared__ alignas(16) u16 Asm[128 * 64];
    __shared__ alignas(16) u16 Bsm[128 * 64];
    int p0 = ptile * 128, o0 = otile * 128;
    int t = threadIdx.x, lane = t & 63, wv = t >> 6;
    int wm = (wv >> 1) * 64, wn = (wv & 1) * 64;
    int l7 = lane & 7;
    int srcoff = (lane >> 3) * 256 + (((lane & 7) ^ (lane >> 3)) * 8);
    int arow = lane & 15, kgrp = lane >> 4;
    f32x4 zero = {0.f, 0.f, 0.f, 0.f};
    f32x4 acc[4][4];
#pragma unroll
    for (int i = 0; i < 4; ++i)
#pragma unroll
        for (int jj = 0; jj < 4; ++jj) acc[i][jj] = zero;

    for (int k0 = 0; k0 < 256; k0 += 64) {
        __syncthreads();
#pragma unroll
        for (int it = 0; it < 4; ++it) {
            int r0 = it * 32 + wv * 8;
            gload16(A + (size_t)(p0 + r0) * 256 + k0 + srcoff, &Asm[r0 * 64]);
            gload16(Bw + (size_t)(o0 + r0) * 256 + k0 + srcoff, &Bsm[r0 * 64]);
        }
        __syncthreads();
#pragma unroll
        for (int kk = 0; kk < 64; kk += 32) {
            int soff = (((kk >> 3) + kgrp) ^ l7) << 3;
            bf16x8 af[4], bfv[4];
#pragma unroll
            for (int mi = 0; mi < 4; ++mi)
                af[mi] = *(const bf16x8*)&Asm[(wm + mi * 16 + arow) * 64 + soff];
#pragma unroll
            for (int ni = 0; ni < 4; ++ni)
                bfv[ni] = *(const bf16x8*)&Bsm[(wn + ni * 16 + arow) * 64 + soff];
#pragma unroll
            for (int mi = 0; mi < 4; ++mi)
#pragma unroll
                for (int ni = 0; ni < 4; ++ni)
                    acc[mi][ni] = __builtin_amdgcn_mfma_f32_16x16x32_bf16(
                        af[mi], bfv[ni], acc[mi][ni], 0, 0, 0);
        }
    }
#pragma unroll
    for (int mi = 0; mi < 4; ++mi) {
#pragma unroll
        for (int ni = 0; ni < 4; ++ni) {
            int col = o0 + wn + ni * 16 + arow;
            float bv = bias[col];
#pragma unroll
            for (int r = 0; r < 4; ++r) {
                int row = p0 + wm + mi * 16 + ((lane >> 4) << 2) + r;
                float v = acc[mi][ni][r] + bv;
                if (MODE == 1) {
                    bOut[(size_t)row * 256 + col] = f2bf(v);
                } else {
                    fOut[((size_t)((row >> 12) * 256 + col)) * 4096 + (row & 4095)] = v;
                }
            }
        }
    }
}

// ---------------- host ----------------
extern "C" void kernel_launch(void* const* d_in, const int* in_sizes, int n_in,
                              void* d_out, int out_size, void* d_ws, size_t ws_size,
                              hipStream_t stream) {
    const float* x   = (const float*)d_in[0];
    const float* qWw = (const float*)d_in[1];
    const float* qWb = (const float*)d_in[2];
    const float* qHw = (const float*)d_in[3];
    const float* qHb = (const float*)d_in[4];
    const float* fWw = (const float*)d_in[5];
    const float* fWb = (const float*)d_in[6];
    const float* fHw = (const float*)d_in[7];
    const float* fHb = (const float*)d_in[8];
    float* out = (float*)d_out;

    char* ws = (char*)d_ws;
    size_t off = 0;
    auto carve = [&](size_t bytes) -> void* {
        off = (off + 255) & ~(size_t)255;
        void* p = ws + off;
        off += bytes;
        return p;
    };
    const size_t P = 65536;
    u16*   xp  = (u16*)carve(P * 256 * 2);   // x'
    u16*   kb  = (u16*)carve(P * 256 * 2);   // G (both stages)
    u16*   vb  = (u16*)carve(P * 256 * 2);   // x_w'
    float* wq01 = (float*)carve(256 * 4);
    u16*   wkv1 = (u16*)carve(512 * 256 * 2);
    float* bkv1 = (float*)carve(512 * 4);
    u16*   wf1  = (u16*)carve(65536 * 2);
    float* bf1  = (float*)carve(256 * 4);
    float* wq02 = (float*)carve(256 * 4);
    u16*   wkv2 = (u16*)carve(512 * 256 * 2);
    float* bkv2 = (float*)carve(512 * 4);
    u16*   wf2  = (u16*)carve(65536 * 2);
    float* bf2  = (float*)carve(256 * 4);

    prep_w<<<513, 256, 0, stream>>>(qWw, qWb, fWw, fWb, wq01, wkv1, bkv1, wf1, bf1);
    prep_w<<<513, 256, 0, stream>>>(qHw, qHb, fHw, fHb, wq02, wkv2, bkv2, wf2, bf2);
    transpose_in<<<4096, 256, 0, stream>>>(x, xp);

    // ---- stage 1 (axis = W) ----
    qkv_attn<0><<<512, 512, 0, stream>>>(xp, wkv1, bkv1, wq01, kb);
    gemm_k<1><<<1024, 256, 0, stream>>>(kb, wf1, bf1, vb, nullptr);   // x_w' -> vb
    // ---- stage 2 (axis = H) ----
    qkv_attn<1><<<512, 512, 0, stream>>>(vb, wkv2, bkv2, wq02, kb);
    gemm_k<2><<<1024, 256, 0, stream>>>(kb, wf2, bf2, nullptr, out);
    (void)in_sizes; (void)n_in; (void)out_size; (void)ws_size;
}

// Round 8
// 167.295 us; speedup vs baseline: 1.0948x; 1.0948x over previous
//
#include <hip/hip_runtime.h>

typedef unsigned short u16;
typedef unsigned int u32;
typedef __attribute__((ext_vector_type(8))) short bf16x8;
typedef __attribute__((ext_vector_type(4))) float f32x4;

__device__ __forceinline__ u16 f2bf(float f) {
    u32 u = __builtin_bit_cast(u32, f);
    u += 0x7FFFu + ((u >> 16) & 1u);
    return (u16)(u >> 16);
}
__device__ __forceinline__ float bf2f(u16 s) {
    u32 u = ((u32)s) << 16;
    return __builtin_bit_cast(float, u);
}
__device__ __forceinline__ float sigm(float x) {
    return 1.0f / (1.0f + __expf(-x));
}
__device__ __forceinline__ void gload16(const u16* g, u16* l) {
    __builtin_amdgcn_global_load_lds(
        (const __attribute__((address_space(1))) void*)g,
        (__attribute__((address_space(3))) void*)l, 16, 0, 0);
}

// ---------------- P1: x (B,C,H,W) fp32 -> x' [p][c] bf16, p=(b*64+h)*64+w ----
__global__ __launch_bounds__(256) void transpose_in(const float* __restrict__ x,
                                                    u16* __restrict__ xp) {
    __shared__ float tile[64][65];
    int bid = blockIdx.x;
    int ct = bid & 3, h = (bid >> 2) & 63, b = bid >> 8;
    int t = threadIdx.x;
    int tr = t >> 4, tc = t & 15;
    const float* src = x + (((size_t)(b * 256 + ct * 64) * 64 + h) * 64);
#pragma unroll
    for (int i = 0; i < 4; ++i) {
        int c = tr + i * 16;
        float4 v = *(const float4*)(src + (size_t)c * 4096 + tc * 4);
        tile[c][tc * 4 + 0] = v.x;
        tile[c][tc * 4 + 1] = v.y;
        tile[c][tc * 4 + 2] = v.z;
        tile[c][tc * 4 + 3] = v.w;
    }
    __syncthreads();
    u16* dst = xp + ((size_t)((b * 64 + h) * 64)) * 256 + ct * 64;
#pragma unroll
    for (int i = 0; i < 4; ++i) {
        int w = tr + i * 16;
        ushort4 o;
        o.x = f2bf(tile[tc * 4 + 0][w]);
        o.y = f2bf(tile[tc * 4 + 1][w]);
        o.z = f2bf(tile[tc * 4 + 2][w]);
        o.w = f2bf(tile[tc * 4 + 3][w]);
        *(ushort4*)(dst + (size_t)w * 256 + tc * 4) = o;
    }
}

// ---------------- weight prep ------------------------------------------------
__global__ __launch_bounds__(256) void prep_w(const float* __restrict__ qw,
                                              const float* __restrict__ qb,
                                              const float* __restrict__ fw,
                                              const float* __restrict__ fb,
                                              float* __restrict__ wq0,
                                              u16* __restrict__ wkv,
                                              float* __restrict__ bkv,
                                              u16* __restrict__ wf,
                                              float* __restrict__ bff) {
    int i = blockIdx.x * 256 + threadIdx.x;
    if (i < 513 * 256) {
        int o = i >> 8, c = i & 255;
        float v = qw[i];
        if (o == 0) wq0[c] = v;
        else        wkv[(size_t)(o - 1) * 256 + c] = f2bf(v);
    }
    if (i < 65536) wf[i] = f2bf(fw[i]);
    if (i < 512)   bkv[i] = qb[i + 1];
    if (i < 256)   bff[i] = fb[i];
}

// ---------------- line_ctx: per-line q-dot + softmax + y = sc^T X + ----------
// ----------------           ctx = Wk*y + bk  (ctx out, 1 block per line) -----
template <int AXIS>
__global__ __launch_bounds__(256) void line_ctx(
    const u16* __restrict__ A, const u16* __restrict__ Wk,
    const float* __restrict__ wq0, const float* __restrict__ bkv,
    float* __restrict__ ctx) {
    __shared__ alignas(16) u16 Xl[64 * 256];
    __shared__ float ql[64];
    __shared__ float sc[64];
    __shared__ alignas(16) float ys[256];
    int t = threadIdx.x, lane = t & 63, wv = t >> 6;
    int l = blockIdx.x;
    auto prow = [&](int r) -> size_t {
        if (AXIS == 0) return (size_t)l * 64 + r;
        else           return (size_t)(l >> 6) * 4096 + (size_t)r * 64 + (l & 63);
    };
    // ---- stage line (swizzle: stored chunk = src chunk ^ (row&7)) ----
#pragma unroll
    for (int i = 0; i < 8; ++i) {
        int row = i * 8 + wv * 2 + (lane >> 5);
        int slot = (lane & 31) ^ (row & 7);
        gload16(A + prow(row) * 256 + slot * 8, &Xl[(i * 8 + wv * 2) * 256]);
    }
    __syncthreads();
    // ---- q-dot: 4 threads per row ----
    {
        int row = t >> 2, g = t & 3;
        const float* wp = wq0 + g * 64;
        float a = 0.f;
#pragma unroll
        for (int cc = 0; cc < 8; ++cc) {
            int slot = (g * 8 + cc) ^ (row & 7);
            bf16x8 v = *(const bf16x8*)&Xl[row * 256 + slot * 8];
#pragma unroll
            for (int j = 0; j < 8; ++j) a += bf2f((u16)v[j]) * wp[cc * 8 + j];
        }
        a += __shfl_xor(a, 1);
        a += __shfl_xor(a, 2);
        if (g == 0) ql[row] = a;
    }
    __syncthreads();
    // ---- softmax over 64 (wave 0) ----
    if (t < 64) {
        float qv = ql[t];
        float m = qv;
#pragma unroll
        for (int off = 32; off > 0; off >>= 1) m = fmaxf(m, __shfl_xor(m, off));
        float e = __expf(qv - m);
        float s = e;
#pragma unroll
        for (int off = 32; off > 0; off >>= 1) s += __shfl_xor(s, off);
        sc[t] = e / s;
    }
    __syncthreads();
    // ---- y[c] = sum_p sc[p] * X[p][c]; thread owns channel c = t ----
    {
        int chunk = t >> 3, e7 = t & 7;
        float a = 0.f;
#pragma unroll 8
        for (int p = 0; p < 64; ++p) {
            int slot = chunk ^ (p & 7);
            a += bf2f(Xl[p * 256 + slot * 8 + e7]) * sc[p];
        }
        ys[t] = a;
    }
    __syncthreads();
    // ---- ctx[c] = Wk[c,:].y + bk[c] ----
    {
        const u16* wk = Wk + (size_t)t * 256;
        float a = 0.f;
#pragma unroll
        for (int kc = 0; kc < 32; ++kc) {
            bf16x8 w = *(const bf16x8*)(wk + kc * 8);
#pragma unroll
            for (int j = 0; j < 8; ++j) a += bf2f((u16)w[j]) * ys[kc * 8 + j];
        }
        ctx[(size_t)l * 256 + t] = a + bkv[t];
    }
}

// ---------------- val_gate: G = X + sigmoid(X.Wv^T + bv) * ctx[line] ---------
// Clone of gemm_k structure (proven ~500 TF) + gating epilogue.
template <int AXIS>
__global__ __launch_bounds__(256, 2) void val_gate(
    const u16* __restrict__ A, const u16* __restrict__ Wv,
    const float* __restrict__ bv, const float* __restrict__ ctx,
    u16* __restrict__ G) {
    int h = blockIdx.x;
    int xcd = h & 7, slot = h >> 3;
    int otile = slot & 1, ptile = xcd * 64 + (slot >> 1);
    __shared__ alignas(16) u16 Asm[128 * 64];
    __shared__ alignas(16) u16 Bsm[128 * 64];
    int p0 = ptile * 128, o0 = otile * 128;
    int t = threadIdx.x, lane = t & 63, wv = t >> 6;
    int wm = (wv >> 1) * 64, wn = (wv & 1) * 64;
    int l7 = lane & 7;
    int srcoff = (lane >> 3) * 256 + (((lane & 7) ^ (lane >> 3)) * 8);
    int arow = lane & 15, kgrp = lane >> 4;
    f32x4 zero = {0.f, 0.f, 0.f, 0.f};
    f32x4 acc[4][4];
#pragma unroll
    for (int i = 0; i < 4; ++i)
#pragma unroll
        for (int jj = 0; jj < 4; ++jj) acc[i][jj] = zero;

    for (int k0 = 0; k0 < 256; k0 += 64) {
        __syncthreads();
#pragma unroll
        for (int it = 0; it < 4; ++it) {
            int r0 = it * 32 + wv * 8;
            gload16(A + (size_t)(p0 + r0) * 256 + k0 + srcoff, &Asm[r0 * 64]);
            gload16(Wv + (size_t)(o0 + r0) * 256 + k0 + srcoff, &Bsm[r0 * 64]);
        }
        __syncthreads();
#pragma unroll
        for (int kk = 0; kk < 64; kk += 32) {
            int soff = (((kk >> 3) + kgrp) ^ l7) << 3;
            bf16x8 af[4], bfv[4];
#pragma unroll
            for (int mi = 0; mi < 4; ++mi)
                af[mi] = *(const bf16x8*)&Asm[(wm + mi * 16 + arow) * 64 + soff];
#pragma unroll
            for (int ni = 0; ni < 4; ++ni)
                bfv[ni] = *(const bf16x8*)&Bsm[(wn + ni * 16 + arow) * 64 + soff];
#pragma unroll
            for (int mi = 0; mi < 4; ++mi)
#pragma unroll
                for (int ni = 0; ni < 4; ++ni)
                    acc[mi][ni] = __builtin_amdgcn_mfma_f32_16x16x32_bf16(
                        af[mi], bfv[ni], acc[mi][ni], 0, 0, 0);
        }
    }
#pragma unroll
    for (int mi = 0; mi < 4; ++mi) {
#pragma unroll
        for (int ni = 0; ni < 4; ++ni) {
            int col = o0 + wn + ni * 16 + arow;
            float bias = bv[col];
#pragma unroll
            for (int r = 0; r < 4; ++r) {
                int row = p0 + wm + mi * 16 + (kgrp << 2) + r;
                int line = (AXIS == 0) ? (row >> 6) : ((row >> 12) * 64 + (row & 63));
                float cx = ctx[(size_t)line * 256 + col];
                float xv = bf2f(A[(size_t)row * 256 + col]);
                float v = acc[mi][ni][r] + bias;
                G[(size_t)row * 256 + col] = f2bf(xv + sigm(v) * cx);
            }
        }
    }
}

// ---------------- fusion GEMM: MODE 1 = bf16 out, MODE 2 = fp32 transposed out
template <int MODE>
__global__ __launch_bounds__(256, 2) void gemm_k(
    const u16* __restrict__ A, const u16* __restrict__ Bw,
    const float* __restrict__ bias,
    u16* __restrict__ bOut, float* __restrict__ fOut) {
    int h = blockIdx.x;
    int xcd = h & 7, slot = h >> 3;
    int otile = slot & 1, ptile = xcd * 64 + (slot >> 1);
    __shared__ alignas(16) u16 Asm[128 * 64];
    __shared__ alignas(16) u16 Bsm[128 * 64];
    int p0 = ptile * 128, o0 = otile * 128;
    int t = threadIdx.x, lane = t & 63, wv = t >> 6;
    int wm = (wv >> 1) * 64, wn = (wv & 1) * 64;
    int l7 = lane & 7;
    int srcoff = (lane >> 3) * 256 + (((lane & 7) ^ (lane >> 3)) * 8);
    int arow = lane & 15, kgrp = lane >> 4;
    f32x4 zero = {0.f, 0.f, 0.f, 0.f};
    f32x4 acc[4][4];
#pragma unroll
    for (int i = 0; i < 4; ++i)
#pragma unroll
        for (int jj = 0; jj < 4; ++jj) acc[i][jj] = zero;

    for (int k0 = 0; k0 < 256; k0 += 64) {
        __syncthreads();
#pragma unroll
        for (int it = 0; it < 4; ++it) {
            int r0 = it * 32 + wv * 8;
            gload16(A + (size_t)(p0 + r0) * 256 + k0 + srcoff, &Asm[r0 * 64]);
            gload16(Bw + (size_t)(o0 + r0) * 256 + k0 + srcoff, &Bsm[r0 * 64]);
        }
        __syncthreads();
#pragma unroll
        for (int kk = 0; kk < 64; kk += 32) {
            int soff = (((kk >> 3) + kgrp) ^ l7) << 3;
            bf16x8 af[4], bfv[4];
#pragma unroll
            for (int mi = 0; mi < 4; ++mi)
                af[mi] = *(const bf16x8*)&Asm[(wm + mi * 16 + arow) * 64 + soff];
#pragma unroll
            for (int ni = 0; ni < 4; ++ni)
                bfv[ni] = *(const bf16x8*)&Bsm[(wn + ni * 16 + arow) * 64 + soff];
#pragma unroll
            for (int mi = 0; mi < 4; ++mi)
#pragma unroll
                for (int ni = 0; ni < 4; ++ni)
                    acc[mi][ni] = __builtin_amdgcn_mfma_f32_16x16x32_bf16(
                        af[mi], bfv[ni], acc[mi][ni], 0, 0, 0);
        }
    }
#pragma unroll
    for (int mi = 0; mi < 4; ++mi) {
#pragma unroll
        for (int ni = 0; ni < 4; ++ni) {
            int col = o0 + wn + ni * 16 + arow;
            float bv = bias[col];
#pragma unroll
            for (int r = 0; r < 4; ++r) {
                int row = p0 + wm + mi * 16 + ((lane >> 4) << 2) + r;
                float v = acc[mi][ni][r] + bv;
                if (MODE == 1) {
                    bOut[(size_t)row * 256 + col] = f2bf(v);
                } else {
                    fOut[((size_t)((row >> 12) * 256 + col)) * 4096 + (row & 4095)] = v;
                }
            }
        }
    }
}

// ---------------- host ----------------
extern "C" void kernel_launch(void* const* d_in, const int* in_sizes, int n_in,
                              void* d_out, int out_size, void* d_ws, size_t ws_size,
                              hipStream_t stream) {
    const float* x   = (const float*)d_in[0];
    const float* qWw = (const float*)d_in[1];
    const float* qWb = (const float*)d_in[2];
    const float* qHw = (const float*)d_in[3];
    const float* qHb = (const float*)d_in[4];
    const float* fWw = (const float*)d_in[5];
    const float* fWb = (const float*)d_in[6];
    const float* fHw = (const float*)d_in[7];
    const float* fHb = (const float*)d_in[8];
    float* out = (float*)d_out;

    char* ws = (char*)d_ws;
    size_t off = 0;
    auto carve = [&](size_t bytes) -> void* {
        off = (off + 255) & ~(size_t)255;
        void* p = ws + off;
        off += bytes;
        return p;
    };
    const size_t P = 65536;
    u16*   xp  = (u16*)carve(P * 256 * 2);   // x'
    u16*   kb  = (u16*)carve(P * 256 * 2);   // G (both stages)
    u16*   vb  = (u16*)carve(P * 256 * 2);   // x_w'
    float* ctxb = (float*)carve(1024 * 256 * 4);
    float* wq01 = (float*)carve(256 * 4);
    u16*   wkv1 = (u16*)carve(512 * 256 * 2);
    float* bkv1 = (float*)carve(512 * 4);
    u16*   wf1  = (u16*)carve(65536 * 2);
    float* bf1  = (float*)carve(256 * 4);
    float* wq02 = (float*)carve(256 * 4);
    u16*   wkv2 = (u16*)carve(512 * 256 * 2);
    float* bkv2 = (float*)carve(512 * 4);
    u16*   wf2  = (u16*)carve(65536 * 2);
    float* bf2  = (float*)carve(256 * 4);

    prep_w<<<513, 256, 0, stream>>>(qWw, qWb, fWw, fWb, wq01, wkv1, bkv1, wf1, bf1);
    prep_w<<<513, 256, 0, stream>>>(qHw, qHb, fHw, fHb, wq02, wkv2, bkv2, wf2, bf2);
    transpose_in<<<4096, 256, 0, stream>>>(x, xp);

    // ---- stage 1 (axis = W) ----
    line_ctx<0><<<1024, 256, 0, stream>>>(xp, wkv1, wq01, bkv1, ctxb);
    val_gate<0><<<1024, 256, 0, stream>>>(xp, wkv1 + 256 * 256, bkv1 + 256,
                                          ctxb, kb);
    gemm_k<1><<<1024, 256, 0, stream>>>(kb, wf1, bf1, vb, nullptr);   // x_w' -> vb
    // ---- stage 2 (axis = H) ----
    line_ctx<1><<<1024, 256, 0, stream>>>(vb, wkv2, wq02, bkv2, ctxb);
    val_gate<1><<<1024, 256, 0, stream>>>(vb, wkv2 + 256 * 256, bkv2 + 256,
                                          ctxb, kb);
    gemm_k<2><<<1024, 256, 0, stream>>>(kb, wf2, bf2, nullptr, out);
    (void)in_sizes; (void)n_in; (void)out_size; (void)ws_size;
}